// Round 5
// baseline (1232.410 us; speedup 1.0000x reference)
//
#include <hip/hip_runtime.h>
#include <cstdio>

#define BB 4
#define C 64
#define HH 192
#define WW 192
#define NPIX (HH*WW)            /* 36864 */
#define ST (BB*C*NPIX)          /* 9437184 floats per tensor */

__device__ __forceinline__ float gelu_f(float v) {
    return 0.5f * v * (1.0f + erff(v * 0.70710678118654752440f));
}

// ---------------------------------------------------------------------------
// Generic 1x1 conv over NCHW: out[b,o,n] = W1@in1 (+ W2@in2) (+bias1)(+bias2)
// grid = (NPIX/256, B), block = 256. out1 never aliases inputs.
// ---------------------------------------------------------------------------
template<bool TWO_IN>
__global__ __launch_bounds__(256) void k_conv(
    const float* __restrict__ in1, const float* __restrict__ in2,
    const float* __restrict__ W1, const float* __restrict__ W2,
    const float* __restrict__ bias1, const float* __restrict__ bias2,
    float* __restrict__ out1)
{
    const int n = blockIdx.x * 256 + threadIdx.x;
    const int b = blockIdx.y;
    const int base = b * (C * NPIX) + n;
    float xv[C];
#pragma unroll
    for (int c = 0; c < C; ++c) xv[c] = in1[base + c * NPIX];
    float yv[TWO_IN ? C : 1];
    if (TWO_IN) {
#pragma unroll
        for (int c = 0; c < C; ++c) yv[c] = in2[base + c * NPIX];
    }
    for (int o = 0; o < C; ++o) {
        const float* wr = W1 + o * C;
        float a0 = 0.f, a1 = 0.f, a2 = 0.f, a3 = 0.f;
#pragma unroll
        for (int c = 0; c < C; c += 4) {
            a0 += wr[c+0] * xv[c+0];
            a1 += wr[c+1] * xv[c+1];
            a2 += wr[c+2] * xv[c+2];
            a3 += wr[c+3] * xv[c+3];
        }
        if (TWO_IN) {
            const float* wr2 = W2 + o * C;
#pragma unroll
            for (int c = 0; c < C; c += 4) {
                a0 += wr2[c+0] * yv[c+0];
                a1 += wr2[c+1] * yv[c+1];
                a2 += wr2[c+2] * yv[c+2];
                a3 += wr2[c+3] * yv[c+3];
            }
        }
        float acc = (a0 + a1) + (a2 + a3);
        if (bias1) acc += bias1[o];
        if (bias2) acc += bias2[o];
        out1[base + o * NPIX] = acc;
    }
}

// ---------------------------------------------------------------------------
// Final fused conv: out = gelu(Wxb[b]@x1 + W2b[b]@Z2' + W3b[b]@Z3' + fb).
// All three weight mats are per-batch 64x64. grid (NPIX/256, B), block 256.
// ---------------------------------------------------------------------------
__global__ __launch_bounds__(256) void k_conv3(
    const float* __restrict__ in1, const float* __restrict__ in2,
    const float* __restrict__ in3,
    const float* __restrict__ W1, const float* __restrict__ W2,
    const float* __restrict__ W3, const float* __restrict__ bias,
    float* __restrict__ out)
{
    const int n = blockIdx.x * 256 + threadIdx.x;
    const int b = blockIdx.y;
    const int base = b * (C * NPIX) + n;
    float xv[C], yv[C], zv[C];
#pragma unroll
    for (int c = 0; c < C; ++c) xv[c] = in1[base + c * NPIX];
#pragma unroll
    for (int c = 0; c < C; ++c) yv[c] = in2[base + c * NPIX];
#pragma unroll
    for (int c = 0; c < C; ++c) zv[c] = in3[base + c * NPIX];
    const float* w1 = W1 + b * 4096;
    const float* w2 = W2 + b * 4096;
    const float* w3 = W3 + b * 4096;
    for (int o = 0; o < C; ++o) {
        const float* r1 = w1 + o * C;
        const float* r2 = w2 + o * C;
        const float* r3 = w3 + o * C;
        float a0 = 0.f, a1 = 0.f, a2 = 0.f, a3 = 0.f;
#pragma unroll
        for (int c = 0; c < C; c += 4) {
            a0 += r1[c+0] * xv[c+0];
            a1 += r1[c+1] * xv[c+1];
            a2 += r1[c+2] * xv[c+2];
            a3 += r1[c+3] * xv[c+3];
        }
#pragma unroll
        for (int c = 0; c < C; c += 4) {
            a0 += r2[c+0] * yv[c+0];
            a1 += r2[c+1] * yv[c+1];
            a2 += r2[c+2] * yv[c+2];
            a3 += r2[c+3] * yv[c+3];
        }
#pragma unroll
        for (int c = 0; c < C; c += 4) {
            a0 += r3[c+0] * zv[c+0];
            a1 += r3[c+1] * zv[c+1];
            a2 += r3[c+2] * zv[c+2];
            a3 += r3[c+3] * zv[c+3];
        }
        out[base + o * NPIX] = gelu_f((a0 + a1) + (a2 + a3) + bias[o]);
    }
}

// ---------------------------------------------------------------------------
// Depthwise 3x3 (pad 1) + bias + GELU.  grid = (H, B*C), block = 192 (=W).
// ---------------------------------------------------------------------------
__global__ __launch_bounds__(192) void k_dw(
    const float* __restrict__ t0, const float* __restrict__ w,
    const float* __restrict__ bias, float* __restrict__ g)
{
    const int x = threadIdx.x;
    const int y = blockIdx.x;
    const int bc = blockIdx.y;
    const int c = bc & 63;
    const float* img = t0 + bc * NPIX;
    const float* wc = w + c * 9;
    float acc = bias[c];
#pragma unroll
    for (int dy = -1; dy <= 1; ++dy) {
        const int yy = y + dy;
        if (yy < 0 || yy > 191) continue;
#pragma unroll
        for (int dx = -1; dx <= 1; ++dx) {
            const int xx = x + dx;
            if (xx < 0 || xx > 191) continue;
            acc += img[yy*WW + xx] * wc[(dy+1)*3 + (dx+1)];
        }
    }
    g[bc*NPIX + y*WW + x] = gelu_f(acc);
}

// ---------------------------------------------------------------------------
// Per-batch Gram G1 = X1 * X1^T: partial per 256-pixel chunk.
// ---------------------------------------------------------------------------
__global__ __launch_bounds__(256) void k_gram_part(
    const float* __restrict__ x1p, float* __restrict__ part)
{
    extern __shared__ float lt[];     // [256][68]
    const int chunk = blockIdx.x, b = blockIdx.y, t = threadIdx.x;
    const int gbase = b * (C*NPIX) + chunk * 256;
    for (int idx = t; idx < C*256; idx += 256) {
        const int c = idx >> 8, n = idx & 255;
        lt[n*68 + c] = x1p[gbase + c*NPIX + n];
    }
    __syncthreads();
    const int ti = t & 15, tj = t >> 4;
    float acc[4][4];
#pragma unroll
    for (int r = 0; r < 4; ++r)
#pragma unroll
        for (int s = 0; s < 4; ++s) acc[r][s] = 0.f;
    for (int n = 0; n < 256; ++n) {
        const float4 av = *reinterpret_cast<const float4*>(&lt[n*68 + 4*ti]);
        const float4 bv = *reinterpret_cast<const float4*>(&lt[n*68 + 4*tj]);
        const float ar[4] = {av.x, av.y, av.z, av.w};
        const float br[4] = {bv.x, bv.y, bv.z, bv.w};
#pragma unroll
        for (int r = 0; r < 4; ++r)
#pragma unroll
            for (int s = 0; s < 4; ++s) acc[r][s] += ar[r] * br[s];
    }
    float* pb = part + (b*144 + chunk)*4096;
#pragma unroll
    for (int r = 0; r < 4; ++r)
#pragma unroll
        for (int s = 0; s < 4; ++s) pb[(4*ti+r)*64 + (4*tj+s)] = acc[r][s];
}

__global__ __launch_bounds__(256) void k_gram_reduce(
    const float* __restrict__ part, float* __restrict__ G1)
{
    const int flat = blockIdx.x*256 + threadIdx.x;   // < 16384
    const int b = flat >> 12, ij = flat & 4095;
    float s = 0.f;
    for (int ch = 0; ch < 144; ++ch) s += part[(b*144+ch)*4096 + ij];
    G1[flat] = s;
}

// ---------------------------------------------------------------------------
// Channel-attention collapse: per batch, M2 = Wp * blockdiag(attn) * Wv.
// ---------------------------------------------------------------------------
__global__ __launch_bounds__(256) void k_attn_small(
    const float* __restrict__ G1a, const float* __restrict__ Wq,
    const float* __restrict__ Wk, const float* __restrict__ Wv,
    const float* __restrict__ Wp, const float* __restrict__ temp,
    float* __restrict__ M2)
{
    extern __shared__ float sm[];
    float* g1 = sm;
    float* wa = sm + 4096;
    float* wb = sm + 8192;
    float* u  = sm + 12288;
    float* at = sm + 16384;
    float* nq = sm + 18432;
    float* nk = sm + 18496;
    const int b = blockIdx.x, t = threadIdx.x;
    const float* G = G1a + b*4096;
    for (int i = t; i < 4096; i += 256) { g1[i] = G[i]; wa[i] = Wq[i]; wb[i] = Wk[i]; }
    __syncthreads();
    {
        const int r = t >> 2, q4 = t & 3;
        for (int cc = q4*16; cc < q4*16 + 16; ++cc) {
            float s = 0.f;
            for (int k = 0; k < 64; ++k) s += wa[r*64+k] * g1[k*64+cc];
            u[r*64+cc] = s;
        }
    }
    __syncthreads();
    {
        const int d = t >> 2, kq = t & 3;
        float p = 0.f;
        for (int k = kq*16; k < kq*16 + 16; ++k) {
            float tk = 0.f;
            for (int c2 = 0; c2 < 64; ++c2) tk += g1[k*64+c2] * wb[d*64+c2];
            p += wb[d*64+k] * tk;
        }
        p += __shfl_xor(p, 1);
        p += __shfl_xor(p, 2);
        if (kq == 0) nk[d] = sqrtf(fmaxf(p, 0.f));
    }
    if (t < 64) {
        float s = 0.f;
        for (int c2 = 0; c2 < 64; ++c2) s += u[t*64+c2] * wa[t*64+c2];
        nq[t] = sqrtf(fmaxf(s, 0.f));
    }
    __syncthreads();
    if (t < 64) {
        const int gI = t >> 5;
        const float tg = temp[gI];
        const float dq = fmaxf(nq[t], 1e-12f);
        float row[32];
        float mx = -1e30f;
#pragma unroll
        for (int d2 = 0; d2 < 32; ++d2) {
            const int dd = gI*32 + d2;
            float s = 0.f;
            for (int c2 = 0; c2 < 64; ++c2) s += u[t*64+c2] * wb[dd*64+c2];
            s = s * tg / (dq * fmaxf(nk[dd], 1e-12f));
            row[d2] = s; mx = fmaxf(mx, s);
        }
        float se = 0.f;
#pragma unroll
        for (int d2 = 0; d2 < 32; ++d2) { row[d2] = __expf(row[d2]-mx); se += row[d2]; }
        const float inv = 1.f / se;
#pragma unroll
        for (int d2 = 0; d2 < 32; ++d2) at[t*32+d2] = row[d2]*inv;
    }
    __syncthreads();
    for (int i = t; i < 4096; i += 256) { wa[i] = Wv[i]; wb[i] = Wp[i]; }
    __syncthreads();
    {
        const int m = t >> 2, q4 = t & 3, gI = m >> 5;
        for (int e = q4*16; e < q4*16 + 16; ++e) {
            float s = 0.f;
#pragma unroll
            for (int d2 = 0; d2 < 32; ++d2) s += at[m*32+d2] * wa[(gI*32+d2)*64 + e];
            g1[m*64+e] = s;
        }
    }
    __syncthreads();
    {
        const int o = t >> 2, q4 = t & 3;
        for (int e = q4*16; e < q4*16 + 16; ++e) {
            float s = 0.f;
            for (int m = 0; m < 64; ++m) s += wb[o*64+m] * g1[m*64+e];
            M2[b*4096 + o*64+e] = s;
        }
    }
}

// ---------------------------------------------------------------------------
// Small weight-folding products:
//  0: Wtr = rq^T rk   1: Wtc = cq^T ck
//  2: Wf2p = gr * Wf[:,64:128] @ rv   3: Wf3p = gc * Wf[:,128:192] @ cv
//  4: Wfx  = Wf[:,64:128] + Wf[:,128:192]
// ---------------------------------------------------------------------------
__global__ __launch_bounds__(256) void k_small_mats(
    const float* __restrict__ rq, const float* __restrict__ rk,
    const float* __restrict__ cq, const float* __restrict__ ck,
    const float* __restrict__ fw, const float* __restrict__ rv,
    const float* __restrict__ cv, const float* __restrict__ rg,
    const float* __restrict__ cg,
    float* __restrict__ Wtr, float* __restrict__ Wtc,
    float* __restrict__ Wf2p, float* __restrict__ Wf3p,
    float* __restrict__ Wfx)
{
    const int which = blockIdx.x, t = threadIdx.x;
    const int a = t >> 2, b0 = (t & 3) * 16;
    if (which <= 1) {
        const float* Q = which ? cq : rq;
        const float* Kw = which ? ck : rk;
        float* O = which ? Wtc : Wtr;
        for (int b = b0; b < b0 + 16; ++b) {
            float s = 0.f;
            for (int co = 0; co < 64; ++co) s += Q[co*64 + a] * Kw[co*64 + b];
            O[a*64 + b] = s;
        }
    } else if (which <= 3) {
        const float* Vw = (which == 2) ? rv : cv;
        const float g = (which == 2) ? rg[0] : cg[0];
        const int off = (which == 2) ? 64 : 128;
        float* O = (which == 2) ? Wf2p : Wf3p;
        for (int b = b0; b < b0 + 16; ++b) {
            float s = 0.f;
            for (int m = 0; m < 64; ++m) s += fw[a*192 + off + m] * Vw[m*64 + b];
            O[a*64 + b] = g * s;
        }
    } else {
        for (int b = b0; b < b0 + 16; ++b)
            Wfx[a*64 + b] = fw[a*192 + 64 + b] + fw[a*192 + 128 + b];
    }
}

// ---------------------------------------------------------------------------
// Fold M2 into the final-conv weights (per batch):
//  0: Wxb[b] = fw[:,0:64] @ M2[b] + Wfx
//  1: W2b[b] = Wf2p @ M2[b]
//  2: W3b[b] = Wf3p @ M2[b]
// grid (3, B), block 256.
// ---------------------------------------------------------------------------
__global__ __launch_bounds__(256) void k_fold_mats(
    const float* __restrict__ fw, const float* __restrict__ Wfx,
    const float* __restrict__ Wf2p, const float* __restrict__ Wf3p,
    const float* __restrict__ M2,
    float* __restrict__ Wxb, float* __restrict__ W2b, float* __restrict__ W3b)
{
    const int which = blockIdx.x, b = blockIdx.y, t = threadIdx.x;
    const int a = t >> 2, e0 = (t & 3) * 16;
    const float* M = M2 + b * 4096;
    if (which == 0) {
        for (int e = e0; e < e0 + 16; ++e) {
            float s = Wfx[a*64 + e];
            for (int m = 0; m < 64; ++m) s += fw[a*192 + m] * M[m*64 + e];
            Wxb[b*4096 + a*64 + e] = s;
        }
    } else if (which == 1) {
        for (int e = e0; e < e0 + 16; ++e) {
            float s = 0.f;
            for (int m = 0; m < 64; ++m) s += Wf2p[a*64 + m] * M[m*64 + e];
            W2b[b*4096 + a*64 + e] = s;
        }
    } else {
        for (int e = e0; e < e0 + 16; ++e) {
            float s = 0.f;
            for (int m = 0; m < 64; ++m) s += Wf3p[a*64 + m] * M[m*64 + e];
            W3b[b*4096 + a*64 + e] = s;
        }
    }
}

// ---------------------------------------------------------------------------
// FUSED per-line attention, both directions in one launch (blockIdx.z).
// Y = Wt@X (LDS), S = X^T Y, P = softmax_rows(S) (shuffle-reduced, kept in
// LDS), Z'[c][i] = sum_j X[c][j] * P[i][j] -> global (U == X after the M2
// commutation fold; M2 is applied via the folded final-conv weights).
// grid (192, B, 2), block = 256.
// LDS (floats): phase A: Xl[64][196]@0, Yl[64][196]@12544, Wl[64][68]@25088
//               phase B: Pl[192][196]@0 (overlay), Ul[64][36]@37632
// dyn LDS = 39936*4 = 159744 B -> 1 block/CU.
// Softmax thread map: ti = t>>4 so a score-row's 16 owners are lanes
// (16*g..16*g+15) of one wave -> __shfl_xor{1,2,4,8} row reduction, and the
// X-operand LDS reads in the S phase are wave-broadcast (conflict-free).
// ---------------------------------------------------------------------------
#define SP 196
#define US 36
__global__ __launch_bounds__(256, 1) void k_attn2(
    const float* __restrict__ X0, const float* __restrict__ Wt0,
    float* __restrict__ Z0,
    const float* __restrict__ X1, const float* __restrict__ Wt1,
    float* __restrict__ Z1)
{
    extern __shared__ float sm[];
    float* Xl = sm;                    // [64][196]
    float* Yl = sm + 12544;            // [64][196]
    float* Wl = sm + 25088;            // [64][68]  Wl[c2][c] = Wt[c][c2]
    float* Pl = sm;                    // [192][196] overlay (phase B)
    float* Ul = sm + 37632;            // [64][36]
    const int t = threadIdx.x;
    const int h = blockIdx.x, b = blockIdx.y;
    const float* X  = blockIdx.z ? X1 : X0;
    const float* Wt = blockIdx.z ? Wt1 : Wt0;
    float* Z        = blockIdx.z ? Z1 : Z0;
    const size_t gbase = (size_t)b*(C*NPIX) + (size_t)h*WW;

    // --- phase 0: load X line + W~ ---
#pragma unroll 4
    for (int k = 0; k < 48; ++k) {
        const int idx = k*256 + t;
        const int c = idx / 192, j = idx - c*192;
        Xl[c*SP + j] = X[gbase + (size_t)c*NPIX + j];
    }
#pragma unroll
    for (int k = 0; k < 16; ++k) {
        const int idx = k*256 + t;                 // idx = a*64 + c2
        Wl[(idx & 63)*68 + (idx >> 6)] = Wt[idx];
    }
    __syncthreads();

    // --- phase 1: Y = Wt @ X, 16x16 thread grid, 4x12 register tiles ---
    {
        const int tc = t & 15, tjy = t >> 4;
        const int c0 = 4*tc, j0y = 12*tjy;
        float accy[4][12];
#pragma unroll
        for (int k = 0; k < 4; ++k)
#pragma unroll
            for (int m = 0; m < 12; ++m) accy[k][m] = 0.f;
        for (int c2 = 0; c2 < 64; ++c2) {
            const float4 w4 = *reinterpret_cast<const float4*>(&Wl[c2*68 + c0]);
            const float4 xa = *reinterpret_cast<const float4*>(&Xl[c2*SP + j0y]);
            const float4 xb = *reinterpret_cast<const float4*>(&Xl[c2*SP + j0y + 4]);
            const float4 xc = *reinterpret_cast<const float4*>(&Xl[c2*SP + j0y + 8]);
            const float wr[4]  = {w4.x, w4.y, w4.z, w4.w};
            const float xr[12] = {xa.x,xa.y,xa.z,xa.w, xb.x,xb.y,xb.z,xb.w,
                                  xc.x,xc.y,xc.z,xc.w};
#pragma unroll
            for (int k = 0; k < 4; ++k)
#pragma unroll
                for (int m = 0; m < 12; ++m) accy[k][m] += wr[k] * xr[m];
        }
#pragma unroll
        for (int k = 0; k < 4; ++k) {
            float4 o0, o1, o2;
            o0.x = accy[k][0]; o0.y = accy[k][1]; o0.z = accy[k][2];  o0.w = accy[k][3];
            o1.x = accy[k][4]; o1.y = accy[k][5]; o1.z = accy[k][6];  o1.w = accy[k][7];
            o2.x = accy[k][8]; o2.y = accy[k][9]; o2.z = accy[k][10]; o2.w = accy[k][11];
            float* yr = &Yl[(c0+k)*SP + j0y];
            *reinterpret_cast<float4*>(yr)     = o0;
            *reinterpret_cast<float4*>(yr + 4) = o1;
            *reinterpret_cast<float4*>(yr + 8) = o2;
        }
    }
    __syncthreads();

    // --- phase 2: S = X^T Y, 12x12 per thread (ti = t>>4 for shuffle rows) ---
    const int ti = t >> 4, tj = t & 15;
    const int i0 = ti*12, j0 = tj*12;
    float acc[12][12];
#pragma unroll
    for (int r = 0; r < 12; ++r)
#pragma unroll
        for (int s = 0; s < 12; ++s) acc[r][s] = 0.f;
#pragma unroll 2
    for (int c = 0; c < 64; ++c) {
        const float4 xa = *reinterpret_cast<const float4*>(&Xl[c*SP + i0]);
        const float4 xb = *reinterpret_cast<const float4*>(&Xl[c*SP + i0 + 4]);
        const float4 xc = *reinterpret_cast<const float4*>(&Xl[c*SP + i0 + 8]);
        const float4 ya = *reinterpret_cast<const float4*>(&Yl[c*SP + j0]);
        const float4 yb = *reinterpret_cast<const float4*>(&Yl[c*SP + j0 + 4]);
        const float4 yc = *reinterpret_cast<const float4*>(&Yl[c*SP + j0 + 8]);
        const float xr[12] = {xa.x,xa.y,xa.z,xa.w, xb.x,xb.y,xb.z,xb.w, xc.x,xc.y,xc.z,xc.w};
        const float yr[12] = {ya.x,ya.y,ya.z,ya.w, yb.x,yb.y,yb.z,yb.w, yc.x,yc.y,yc.z,yc.w};
#pragma unroll
        for (int r = 0; r < 12; ++r)
#pragma unroll
            for (int s = 0; s < 12; ++s) acc[r][s] += xr[r] * yr[s];
    }

    // --- phase 3: softmax per row via wave shuffles (no LDS, no barriers) ---
#pragma unroll
    for (int r = 0; r < 12; ++r) {
        float pm = acc[r][0];
#pragma unroll
        for (int s = 1; s < 12; ++s) pm = fmaxf(pm, acc[r][s]);
        pm = fmaxf(pm, __shfl_xor(pm, 1));
        pm = fmaxf(pm, __shfl_xor(pm, 2));
        pm = fmaxf(pm, __shfl_xor(pm, 4));
        pm = fmaxf(pm, __shfl_xor(pm, 8));
        float ps = 0.f;
#pragma unroll
        for (int s = 0; s < 12; ++s) {
            acc[r][s] = __expf(acc[r][s] - pm);
            ps += acc[r][s];
        }
        ps += __shfl_xor(ps, 1);
        ps += __shfl_xor(ps, 2);
        ps += __shfl_xor(ps, 4);
        ps += __shfl_xor(ps, 8);
        const float inv = 1.f / ps;
#pragma unroll
        for (int s = 0; s < 12; ++s) acc[r][s] *= inv;
    }
    __syncthreads();   // all Xl/Yl reads done; Pl may overwrite

    // --- phase 4: store normalized P into LDS ---
#pragma unroll
    for (int r = 0; r < 12; ++r) {
        float4 o0, o1, o2;
        o0.x = acc[r][0];  o0.y = acc[r][1];  o0.z = acc[r][2];  o0.w = acc[r][3];
        o1.x = acc[r][4];  o1.y = acc[r][5];  o1.z = acc[r][6];  o1.w = acc[r][7];
        o2.x = acc[r][8];  o2.y = acc[r][9];  o2.z = acc[r][10]; o2.w = acc[r][11];
        float* pr = &Pl[(i0 + r)*SP + j0];
        *reinterpret_cast<float4*>(pr)     = o0;
        *reinterpret_cast<float4*>(pr + 4) = o1;
        *reinterpret_cast<float4*>(pr + 8) = o2;
    }
    __syncthreads();

    // --- phase 5: Z'[c][i] = sum_j X[c][j] * P[i][j], j tiled by 32 ---
    const int ci = t & 15, ii = t >> 4;
    const int c0z = 4*ci, i0z = 12*ii;
    float accz[4][12];
#pragma unroll
    for (int k = 0; k < 4; ++k)
#pragma unroll
        for (int m = 0; m < 12; ++m) accz[k][m] = 0.f;
    for (int jt = 0; jt < 192; jt += 32) {
#pragma unroll
        for (int k = 0; k < 8; ++k) {       // 64*32/256
            const int idx = k*256 + t;
            const int c = idx >> 5, j = idx & 31;
            Ul[c*US + j] = X[gbase + (size_t)c*NPIX + jt + j];
        }
        __syncthreads();
#pragma unroll 2
        for (int jq = 0; jq < 8; ++jq) {
            float4 u4[4], p4[12];
#pragma unroll
            for (int k = 0; k < 4; ++k)
                u4[k] = *reinterpret_cast<const float4*>(&Ul[(c0z+k)*US + 4*jq]);
#pragma unroll
            for (int m = 0; m < 12; ++m)
                p4[m] = *reinterpret_cast<const float4*>(&Pl[(i0z+m)*SP + jt + 4*jq]);
#pragma unroll
            for (int k = 0; k < 4; ++k)
#pragma unroll
                for (int m = 0; m < 12; ++m) {
                    accz[k][m] += u4[k].x * p4[m].x + u4[k].y * p4[m].y
                                + u4[k].z * p4[m].z + u4[k].w * p4[m].w;
                }
        }
        __syncthreads();
    }
#pragma unroll
    for (int k = 0; k < 4; ++k) {
        float* zr = Z + gbase + (size_t)(c0z + k)*NPIX + i0z;
        float4 o0, o1, o2;
        o0.x = accz[k][0]; o0.y = accz[k][1]; o0.z = accz[k][2];  o0.w = accz[k][3];
        o1.x = accz[k][4]; o1.y = accz[k][5]; o1.z = accz[k][6];  o1.w = accz[k][7];
        o2.x = accz[k][8]; o2.y = accz[k][9]; o2.z = accz[k][10]; o2.w = accz[k][11];
        *reinterpret_cast<float4*>(zr)     = o0;
        *reinterpret_cast<float4*>(zr + 4) = o1;
        *reinterpret_cast<float4*>(zr + 8) = o2;
    }
}

// ---------------------------------------------------------------------------
// HW transpose per image: out[img][x][y] = in[img][y][x]. grid (6,6,B*C).
// ---------------------------------------------------------------------------
__global__ __launch_bounds__(256) void k_transpose(
    const float* __restrict__ in, float* __restrict__ out)
{
    __shared__ float tile[32][33];
    const int tx = threadIdx.x & 31, ty = threadIdx.x >> 5;
    const int x0 = blockIdx.x*32, y0 = blockIdx.y*32;
    const float* img = in + blockIdx.z * NPIX;
    float* og = out + blockIdx.z * NPIX;
#pragma unroll
    for (int r = ty; r < 32; r += 8) tile[r][tx] = img[(y0+r)*WW + x0+tx];
    __syncthreads();
#pragma unroll
    for (int r = ty; r < 32; r += 8) og[(x0+r)*WW + (y0+tx)] = tile[tx][r];
}

// ---------------------------------------------------------------------------
extern "C" void kernel_launch(void* const* d_in, const int* in_sizes, int n_in,
                              void* d_out, int out_size, void* d_ws, size_t ws_size,
                              hipStream_t stream) {
    const float* x       = (const float*)d_in[0];
    const float* pw_w    = (const float*)d_in[1];
    const float* dw_w    = (const float*)d_in[2];
    const float* dw_b    = (const float*)d_in[3];
    const float* conv2_w = (const float*)d_in[4];
    const float* conv2_b = (const float*)d_in[5];
    const float* conv0_w = (const float*)d_in[6];
    const float* conv0_b = (const float*)d_in[7];
    const float* attq    = (const float*)d_in[8];
    const float* attk    = (const float*)d_in[9];
    const float* attv    = (const float*)d_in[10];
    const float* attp    = (const float*)d_in[11];
    const float* temp    = (const float*)d_in[12];
    const float* rq      = (const float*)d_in[13];
    const float* rk      = (const float*)d_in[14];
    const float* rv      = (const float*)d_in[15];
    const float* rg      = (const float*)d_in[16];
    const float* cq      = (const float*)d_in[17];
    const float* ck      = (const float*)d_in[18];
    const float* cv      = (const float*)d_in[19];
    const float* cg      = (const float*)d_in[20];
    const float* fw      = (const float*)d_in[21];
    const float* fb      = (const float*)d_in[22];

    float* ws = (float*)d_ws;
    float* A  = ws;                 // t0 -> x1 (lives to end)
    float* Bf = ws + (size_t)ST;    // g -> Z3t' -> (transposed away)
    float* Cf = ws + 2*(size_t)ST;  // x1t -> Z3'
    float* Df = ws + 3*(size_t)ST;  // Z2'
    float* partials = ws + 4*(size_t)ST;   // 576*4096 = 2359296 floats
    float* G1 = partials + 576*4096;       // 16384
    float* M2 = G1 + 16384;                // 16384
    float* Wtr  = M2 + 16384;              // 5 x 4096 small mats
    float* Wtc  = Wtr + 4096;
    float* Wf2p = Wtc + 4096;
    float* Wf3p = Wf2p + 4096;
    float* Wfx  = Wf3p + 4096;
    float* Wxb  = Wfx + 4096;              // 3 x (B x 4096) folded finals
    float* W2b  = Wxb + BB*4096;
    float* W3b  = W2b + BB*4096;

    const size_t need = ((size_t)4*ST + 576*4096 + 16384 + 16384
                         + 5*4096 + 3*BB*4096) * sizeof(float);
    if (ws_size < need) {
        fprintf(stderr, "kernel_launch: ws_size %zu < needed %zu\n", ws_size, need);
        return;
    }

    (void)hipFuncSetAttribute((const void*)k_gram_part,
        hipFuncAttributeMaxDynamicSharedMemorySize, 69632);
    (void)hipFuncSetAttribute((const void*)k_attn_small,
        hipFuncAttributeMaxDynamicSharedMemorySize, 74240);
    (void)hipFuncSetAttribute((const void*)k_attn2,
        hipFuncAttributeMaxDynamicSharedMemorySize, 159744);

    const dim3 blk256(256), blk192(192);
    const dim3 gconv(NPIX/256, BB);      // (144, 4)
    const dim3 gtr(6, 6, BB*C);

    // 0) fold static weights
    k_small_mats<<<dim3(5), blk256, 0, stream>>>(rq, rk, cq, ck, fw, rv, cv,
                                                 rg, cg, Wtr, Wtc, Wf2p, Wf3p, Wfx);
    // 1) A = t0 = pw_w @ x
    k_conv<false><<<gconv, blk256, 0, stream>>>(
        x, nullptr, pw_w, nullptr, nullptr, nullptr, A);
    // 2) B = g = gelu(dw3x3(A) + dw_b)
    k_dw<<<dim3(HH, BB*C), blk192, 0, stream>>>(A, dw_w, dw_b, Bf);
    // 3) A = x1 = conv2@B + conv0@x + conv2_b + conv0_b   (t0 dead)
    k_conv<true><<<gconv, blk256, 0, stream>>>(
        Bf, x, conv2_w, conv0_w, conv2_b, conv0_b, A);
    // 4) channel attention collapse -> M2, then fold into final weights
    k_gram_part<<<gconv, blk256, 69632, stream>>>(A, partials);
    k_gram_reduce<<<dim3(64), blk256, 0, stream>>>(partials, G1);
    k_attn_small<<<dim3(BB), blk256, 74240, stream>>>(G1, attq, attk, attv, attp, temp, M2);
    k_fold_mats<<<dim3(3, BB), blk256, 0, stream>>>(fw, Wfx, Wf2p, Wf3p, M2,
                                                    Wxb, W2b, W3b);
    // 5) C = x1t
    k_transpose<<<gtr, blk256, 0, stream>>>(A, Cf);
    // 6) both attentions in one launch:
    //    z=0 (row): X=A(x1),  Wtr -> D = Z2'
    //    z=1 (col): X=C(x1t), Wtc -> B = Z3t'   (g dead)
    k_attn2<<<dim3(HH, BB, 2), blk256, 159744, stream>>>(A, Wtr, Df,
                                                         Cf, Wtc, Bf);
    // 7) C = Z3' = transpose(Z3t')   (x1t dead)
    k_transpose<<<gtr, blk256, 0, stream>>>(Bf, Cf);
    // 8) out = gelu(Wxb[b]@x1 + W2b[b]@Z2' + W3b[b]@Z3' + fb)
    k_conv3<<<gconv, blk256, 0, stream>>>(A, Df, Cf, Wxb, W2b, W3b, fb,
                                          (float*)d_out);
}